// Round 14
// baseline (708.330 us; speedup 1.0000x reference)
//
#include <hip/hip_runtime.h>
#include <hip/hip_bf16.h>

typedef const float* fp;
typedef unsigned short u16;
typedef __attribute__((ext_vector_type(8))) short short8v;   // 8 bf16 (4 VGPR)
typedef __attribute__((ext_vector_type(4))) float f32x4;

__device__ __forceinline__ u16 f2b(float f){       // f32 -> bf16 RNE
  union{float f; unsigned u;} x; x.f = f;
  unsigned r = x.u + 0x7FFFu + ((x.u>>16)&1u);
  return (u16)(r>>16);
}
// pack 2 f32 -> 2 bf16 in one u32 (lo=a, hi=b)
__device__ __forceinline__ unsigned pkbf(float a, float b){
  unsigned r;
  asm("v_cvt_pk_bf16_f32 %0, %1, %2" : "=v"(r) : "v"(a), "v"(b));
  return r;
}

// ---------- sentinel fill ----------
__global__ __launch_bounds__(256) void k_fill(float* out, int n, float v){
  int i = blockIdx.x*256 + threadIdx.x;
  if(i < n) out[i] = v;
}
// ---------- per-channel bias fill ----------
__global__ __launch_bounds__(256) void k_fillb(float* out, fp bias, int Cout, int N){
  int i = blockIdx.x*256 + threadIdx.x;
  if(i < 6*Cout*N) out[i] = bias[(i/N)%Cout];
}
// ---------- f32 -> bf16 elementwise ----------
__global__ __launch_bounds__(256) void k_b16(fp in, u16* o, int n){
  int i = (blockIdx.x*256 + threadIdx.x)*8;
  if(i >= n) return;
  u16 tmp[8];
  #pragma unroll
  for(int e=0;e<8;e++) tmp[e] = f2b(in[i+e]);
  *(short8v*)(o+i) = *(const short8v*)tmp;
}
// ---------- conv weight transform: w[Cout][Cin][9] f32 -> wt[9][Cout][Cin] bf16 ----------
__global__ __launch_bounds__(256) void k_wtr(fp w, u16* wt, int Cout, int Cin){
  int idx = blockIdx.x*256 + threadIdx.x;
  int cc = Cout*Cin;
  if(idx >= 9*cc) return;
  int tap = idx / cc, rem = idx - tap*cc;
  wt[idx] = f2b(w[(size_t)rem*9 + tap]);
}
// ---------- qkv weight transform -> BT[3C][C] bf16 (Q rows scaled by log2e/sqrt(C)) ----------
__global__ __launch_bounds__(256) void k_wqkvt(fp wq, fp wk, fp wv, u16* bt, int C, float rs){
  int idx = blockIdx.x*256 + threadIdx.x;
  if(idx >= 3*C*C) return;
  int r = idx / C, ci = idx - r*C;
  int sel = r / C, co = r - sel*C;
  float v = (sel==0 ? wq : sel==1 ? wk : wv)[(size_t)ci*C + co];
  bt[idx] = f2b(sel==0 ? v*rs : v);
}

// ---------- input transpose: x [6,64,768] f32 -> h0 [6,768,64] f32 ----------
__global__ __launch_bounds__(256) void k_in_tr(fp x, float* h0){
  int n = blockIdx.x, b = blockIdx.y;
  for(int d = threadIdx.x; d < 768; d += blockDim.x)
    h0[((size_t)b*768 + d)*64 + n] = x[((size_t)b*64 + n)*768 + d];
}

// ---------- tap-decomposed implicit-GEMM MFMA 3x3 conv, split-K ----------
__global__ __launch_bounds__(256) void k_conv3_mfma2(const u16* __restrict__ wt,
    const u16* __restrict__ inb16, float* __restrict__ out,
    int Cin, int Cout, int H, int W, int S){
  const int N = H*W;
  __shared__ u16 As[64*40];
  __shared__ u16 Bs[64*40];
  int t = threadIdx.x, wid = t>>6, lane = t&63, l15 = lane&15, g = lane>>4;
  int b = blockIdx.z / S, s = blockIdx.z % S;
  int co0 = blockIdx.y*64, px0 = blockIdx.x*64;
  int ciN = Cin/S, ci0 = s*ciN;
  const u16* inb = inb16 + (size_t)b*Cin*N;
  int arow = t>>2, acol = (t&3)*8;
  int bpx = t&63, boct = t>>6;
  int p = px0 + bpx, py = p/W, px_ = p - py*W;
  int nc = ciN >> 5, nk = 9*nc;
  f32x4 acc[4];
  #pragma unroll
  for(int i=0;i<4;i++) acc[i] = f32x4{0.f,0.f,0.f,0.f};
  short8v av; u16 bt[8];

  #define PREF(ks) { int tap = (ks)/nc; int c0 = ((ks) - tap*nc)<<5;                     \
      int dy = tap/3 - 1, dx = tap - (tap/3)*3 - 1;                                      \
      av = *(const short8v*)(wt + ((size_t)tap*Cout + co0 + arow)*Cin + ci0 + c0 + acol);\
      bool val = ((unsigned)(py+dy) < (unsigned)H) && ((unsigned)(px_+dx) < (unsigned)W);\
      const u16* bp = inb + (size_t)(ci0 + c0 + boct*8)*N + (p + dy*W + dx);             \
      _Pragma("unroll") for(int e=0;e<8;e++) bt[e] = val ? bp[(size_t)e*N] : (u16)0; }

  PREF(0);
  for(int ks = 0; ks < nk; ks++){
    __syncthreads();
    *(short8v*)(As + arow*40 + acol) = av;
    *(short8v*)(Bs + bpx*40 + boct*8) = *(const short8v*)bt;
    __syncthreads();
    if(ks+1 < nk) PREF(ks+1);
    short8v a = *(const short8v*)(As + (wid*16+l15)*40 + 8*g);
    #pragma unroll
    for(int pt=0; pt<4; pt++){
      short8v bf = *(const short8v*)(Bs + (pt*16+l15)*40 + 8*g);
      acc[pt] = __builtin_amdgcn_mfma_f32_16x16x32_bf16(a, bf, acc[pt], 0,0,0);
    }
  }
  #undef PREF
  #pragma unroll
  for(int pt=0; pt<4; pt++){
    #pragma unroll
    for(int r=0; r<4; r++){
      size_t o = ((size_t)b*Cout + co0 + wid*16 + 4*g + r)*N + px0 + pt*16 + l15;
      if(S == 1) out[o] = acc[pt][r];
      else atomicAdd(out + o, acc[pt][r]);
    }
  }
}

// ---------- QKV projection GEMM: XB[6N][C] @ BT[3C][C]^T -> Q,K bf16; V stored TRANSPOSED ----------
__global__ __launch_bounds__(256) void k_gemm_qkv(const u16* __restrict__ XB,
    const u16* __restrict__ BT, u16* __restrict__ Qo, u16* __restrict__ Ko,
    u16* __restrict__ Vo, int C, int Nn){
  __shared__ u16 As[64*40], Bs[64*40];
  int t = threadIdx.x, wid = t>>6, lane = t&63, l15 = lane&15, g = lane>>4;
  int r0 = blockIdx.x*64, c0 = blockIdx.y*64;
  int arow = t>>2, acol = (t&3)*8;
  int nk = C/32;
  f32x4 acc[4];
  #pragma unroll
  for(int i=0;i<4;i++) acc[i] = f32x4{0.f,0.f,0.f,0.f};
  short8v av = *(const short8v*)(XB + (size_t)(r0+arow)*C + acol);
  short8v bv = *(const short8v*)(BT + (size_t)(c0+arow)*C + acol);
  for(int ks = 0; ks < nk; ks++){
    __syncthreads();
    *(short8v*)(As + arow*40 + acol) = av;
    *(short8v*)(Bs + arow*40 + acol) = bv;
    __syncthreads();
    if(ks+1 < nk){
      int k0 = (ks+1)*32;
      av = *(const short8v*)(XB + (size_t)(r0+arow)*C + k0 + acol);
      bv = *(const short8v*)(BT + (size_t)(c0+arow)*C + k0 + acol);
    }
    short8v a = *(const short8v*)(As + (wid*16+l15)*40 + 8*g);
    #pragma unroll
    for(int pt=0; pt<4; pt++){
      short8v bf = *(const short8v*)(Bs + (pt*16+l15)*40 + 8*g);
      acc[pt] = __builtin_amdgcn_mfma_f32_16x16x32_bf16(a, bf, acc[pt], 0,0,0);
    }
  }
  int sel = c0 / C, cb = c0 - sel*C;
  if(sel < 2){
    u16* ob = sel==0 ? Qo : Ko;
    #pragma unroll
    for(int pt=0; pt<4; pt++){
      #pragma unroll
      for(int r=0; r<4; r++)
        ob[(size_t)(r0 + wid*16 + 4*g + r)*C + cb + pt*16 + l15] = f2b(acc[pt][r]);
    }
  }else{
    int b = r0 / Nn, nb = r0 - b*Nn;
    #pragma unroll
    for(int pt=0; pt<4; pt++){
      #pragma unroll
      for(int r=0; r<4; r++)
        Vo[((size_t)b*C + cb + pt*16 + l15)*Nn + nb + wid*16 + 4*g + r] = f2b(acc[pt][r]);
    }
  }
}

// ---------- 1x1 conv at LOW res ----------
__global__ void k_conv1_low(const float* __restrict__ in, fp w, fp bias,
                            float* __restrict__ out, int Cin, int Cout, int N1){
  int bc = blockIdx.x; int b = bc / Cout; int co = bc % Cout;
  extern __shared__ float ws[];
  for(int i = threadIdx.x; i < Cin; i += blockDim.x) ws[i] = w[(size_t)co*Cin + i];
  __syncthreads();
  const float* inb = in + (size_t)b*Cin*N1;
  float bv = bias[co];
  for(int p = threadIdx.x; p < N1; p += blockDim.x){
    float acc = bv;
    for(int ci = 0; ci < Cin; ci++) acc += inb[(size_t)ci*N1 + p] * ws[ci];
    out[((size_t)b*Cout + co)*N1 + p] = acc;
  }
}

// ---------- concat channels with up2 replication of low-res part ----------
__global__ __launch_bounds__(256) void k_concat_up(const float* __restrict__ a, fp skip,
                                                   float* __restrict__ cat,
                                                   int Ca, int Cs, int N2, int W2){
  int bc = blockIdx.x; int C = Ca + Cs; int b = bc / C; int c = bc % C;
  float* o = cat + (size_t)bc*N2;
  if(c < Ca){
    const float* s = a + ((size_t)b*Ca + c)*(N2/4);
    int W1 = W2/2;
    for(int n = threadIdx.x; n < N2; n += blockDim.x){
      int y = n / W2, x = n % W2;
      o[n] = s[(y>>1)*W1 + (x>>1)];
    }
  }else{
    fp s = skip + ((size_t)b*Cs + (c-Ca))*N2;
    for(int n = threadIdx.x; n < N2; n += blockDim.x) o[n] = s[n];
  }
}

// ---------- tiled transpose+bf16: [6][C][N] f32 -> [6][N][C] bf16 ----------
__global__ __launch_bounds__(256) void k_trb(const float* __restrict__ src, u16* __restrict__ dst,
                                             int C, int N){
  __shared__ float tb[32][33];
  int b = blockIdx.z;
  int c0 = blockIdx.y*32, n0 = blockIdx.x*32;
  int tx = threadIdx.x & 31, ty = threadIdx.x >> 5;
  for(int i = ty; i < 32; i += 8) tb[i][tx] = src[((size_t)b*C + c0+i)*N + n0+tx];
  __syncthreads();
  for(int i = ty; i < 32; i += 8) dst[((size_t)b*N + n0+i)*C + c0+tx] = f2b(tb[tx][i]);
}

// ---------- MFMA flash attn C=128: exp2 domain, cvt_pk ps stores ----------
__global__ __launch_bounds__(256) void k_attn128(const u16* __restrict__ Q,
                                                 const u16* __restrict__ K,
                                                 const u16* __restrict__ VT,
                                                 float* __restrict__ ctxn, int N){
  constexpr int C = 128, KVB = 64, KP = C+8, VP = KVB+8, PSP = 68;
  __shared__ u16 Ks[KVB*KP];      // [m][c]
  __shared__ u16 Vt[C*VP];        // [c][m]
  __shared__ u16 ps[4][16*PSP];
  int t = threadIdx.x, wid = t>>6, lane = t&63, l15 = lane&15, g = lane>>4;
  int p = blockIdx.y, q0 = (blockIdx.x*4 + wid)*16, j = blockIdx.z;
  const u16* Qb = Q + ((size_t)(p+1)*N + q0)*C;
  const u16* Kb = K  + (size_t)(p + (j?2:0))*N*C;   // [N][C]
  const u16* Vb = VT + (size_t)(p + (j?2:0))*C*N;   // [C][N]
  short8v qf[4];
  #pragma unroll
  for(int kk = 0; kk < 4; kk++)
    qf[kk] = *(const short8v*)(Qb + (size_t)l15*C + kk*32 + 8*g);
  f32x4 acc[8];
  #pragma unroll
  for(int i=0;i<8;i++) acc[i] = f32x4{0.f,0.f,0.f,0.f};
  float m[4] = {-1e30f,-1e30f,-1e30f,-1e30f};
  float l[4] = {0.f,0.f,0.f,0.f};         // lane-local partial sums
  short8v kpre[4], vpre[4];

  #define APREF(M0) { _Pragma("unroll") for(int i=0;i<4;i++){                  \
        int idx = t*8 + i*2048; int mm = idx>>7, cc = idx&127;                 \
        kpre[i] = *(const short8v*)(Kb + (size_t)((M0)+mm)*C + cc); }          \
      _Pragma("unroll") for(int i=0;i<4;i++){                                  \
        int idx = t*8 + i*2048; int c = idx>>6, mo = idx&63;                   \
        vpre[i] = *(const short8v*)(Vb + (size_t)c*N + (M0) + mo); } }

  APREF(0);
  for(int m0 = 0; m0 < N; m0 += KVB){
    __syncthreads();
    #pragma unroll
    for(int i=0;i<4;i++){ int idx = t*8 + i*2048; int mm = idx>>7, cc = idx&127;
      *(short8v*)(Ks + mm*KP + cc) = kpre[i]; }
    #pragma unroll
    for(int i=0;i<4;i++){ int idx = t*8 + i*2048; int c = idx>>6, mo = idx&63;
      *(short8v*)(Vt + c*VP + mo) = vpre[i]; }
    __syncthreads();
    if(m0 + KVB < N) APREF(m0 + KVB);
    f32x4 s[4];
    __builtin_amdgcn_s_setprio(1);
    #pragma unroll
    for(int h=0; h<4; h++){
      s[h] = f32x4{0.f,0.f,0.f,0.f};
      #pragma unroll
      for(int kk=0; kk<4; kk++){
        short8v kf = *(const short8v*)(Ks + (h*16+l15)*KP + kk*32 + 8*g);
        s[h] = __builtin_amdgcn_mfma_f32_16x16x32_bf16(qf[kk], kf, s[h], 0,0,0);
      }
    }
    __builtin_amdgcn_s_setprio(0);
    float lmax[4]; bool need = false;
    #pragma unroll
    for(int r=0; r<4; r++){
      float a = fmaxf(fmaxf(s[0][r],s[1][r]), fmaxf(s[2][r],s[3][r]));
      lmax[r] = a; need |= (a > m[r] + 8.f);
    }
    if(__any((int)need)){
      #pragma unroll
      for(int r=0; r<4; r++){
        float mx = lmax[r];
        #pragma unroll
        for(int off=1; off<16; off<<=1) mx = fmaxf(mx, __shfl_xor(mx, off));
        float mnew = fmaxf(m[r], mx);
        float scl = exp2f(m[r] - mnew);
        l[r] *= scl; m[r] = mnew;
        #pragma unroll
        for(int ct=0; ct<8; ct++) acc[ct][r] *= scl;
      }
    }
    #pragma unroll
    for(int r=0; r<4; r++){
      float e0 = exp2f(s[0][r]-m[r]), e1 = exp2f(s[1][r]-m[r]);
      float e2 = exp2f(s[2][r]-m[r]), e3 = exp2f(s[3][r]-m[r]);
      unsigned pk01 = pkbf(e0,e1), pk23 = pkbf(e2,e3);
      u16* pr = ps[wid] + (4*g+r)*PSP + l15;
      pr[0]  = (u16)pk01; pr[16] = (u16)(pk01>>16);
      pr[32] = (u16)pk23; pr[48] = (u16)(pk23>>16);
      l[r] += (e0+e1)+(e2+e3);
    }
    __builtin_amdgcn_s_setprio(1);
    #pragma unroll
    for(int ks=0; ks<2; ks++){
      short8v pa = *(const short8v*)(ps[wid] + l15*PSP + ks*32 + 8*g);
      #pragma unroll
      for(int ct=0; ct<8; ct++){
        short8v vb = *(const short8v*)(Vt + (ct*16+l15)*VP + ks*32 + 8*g);
        acc[ct] = __builtin_amdgcn_mfma_f32_16x16x32_bf16(pa, vb, acc[ct], 0,0,0);
      }
    }
    __builtin_amdgcn_s_setprio(0);
  }
  #undef APREF
  float inv[4];
  #pragma unroll
  for(int r=0; r<4; r++){
    float lr = l[r];
    #pragma unroll
    for(int off=1; off<16; off<<=1) lr += __shfl_xor(lr, off);
    inv[r] = 0.5f/lr;
  }
  #pragma unroll
  for(int ct=0; ct<8; ct++){
    int c = ct*16 + l15;
    #pragma unroll
    for(int r=0; r<4; r++)
      atomicAdd(&ctxn[((size_t)p*N + q0 + 4*g + r)*C + c], acc[ct][r]*inv[r]);
  }
}

// ---------- MFMA flash attn, in-block KV-split-2 (C=256), exp2 domain ----------
template<int C, bool VL>
__global__ __launch_bounds__(256) void k_attn_sp(const u16* __restrict__ Q,
    const u16* __restrict__ K, const u16* __restrict__ VT,
    float* __restrict__ ctxn, int N){
  constexpr int KVB = 32, KP = C+8, VP = 40, PSP = 40, NP = C/32, CP4 = C+4;
  __shared__ u16 Ks[2*KVB*KP];
  __shared__ u16 Vt[VL ? 2*C*VP : 8];
  __shared__ u16 ps[4][16*PSP];
  int t = threadIdx.x, wid = t>>6, lane = t&63, l15 = lane&15, g = lane>>4;
  int half = wid & 1, qgrp = wid >> 1;
  int lt = ((t>>7)<<6) | (t&63);
  int p = blockIdx.y, j = blockIdx.z;
  int q0 = (blockIdx.x*2 + qgrp)*16;
  const u16* Qb = Q + ((size_t)(p+1)*N + q0)*C;
  const u16* Kb = K  + (size_t)(p + (j?2:0))*N*C;
  const u16* Vb = VT + (size_t)(p + (j?2:0))*C*N;
  u16* Ksh = Ks + half*(KVB*KP);
  u16* Vth = Vt + (VL ? half*(C*VP) : 0);
  int kbase = half*(N>>1);

  short8v qf[NP];
  #pragma unroll
  for(int kk=0;kk<NP;kk++)
    qf[kk] = *(const short8v*)(Qb + (size_t)l15*C + kk*32 + 8*g);
  f32x4 acc[C/16];
  #pragma unroll
  for(int i=0;i<C/16;i++) acc[i] = f32x4{0.f,0.f,0.f,0.f};
  float m[4] = {-1e30f,-1e30f,-1e30f,-1e30f};
  float l[4] = {0.f,0.f,0.f,0.f};
  short8v kpre[NP], vpre[NP];

  #define APREF(M0) { _Pragma("unroll") for(int i_=0;i_<NP;i_++){                 \
        int idx = lt*8 + i_*1024; int mm = idx/C, cc = idx - mm*C;                \
        kpre[i_] = *(const short8v*)(Kb + (size_t)((M0)+mm)*C + cc); }            \
      if constexpr(VL){ _Pragma("unroll") for(int i_=0;i_<NP;i_++){               \
        int idx = lt*8 + i_*1024; int c = idx>>5, mo = idx&31;                    \
        vpre[i_] = *(const short8v*)(Vb + (size_t)c*N + (M0) + mo); } } }

  const int nit = N>>6;
  APREF(kbase);
  for(int it = 0; it < nit; ++it){
    int m0 = kbase + it*KVB;
    __syncthreads();
    #pragma unroll
    for(int i_=0;i_<NP;i_++){ int idx = lt*8 + i_*1024; int mm = idx/C, cc = idx - mm*C;
      *(short8v*)(Ksh + mm*KP + cc) = kpre[i_]; }
    if constexpr(VL){
      #pragma unroll
      for(int i_=0;i_<NP;i_++){ int idx = lt*8 + i_*1024; int c = idx>>5, mo = idx&31;
        *(short8v*)(Vth + c*VP + mo) = vpre[i_]; }
    }
    __syncthreads();
    if(it+1 < nit) APREF(kbase + (it+1)*KVB);
    f32x4 s[2];
    __builtin_amdgcn_s_setprio(1);
    #pragma unroll
    for(int h=0; h<2; h++){
      s[h] = f32x4{0.f,0.f,0.f,0.f};
      #pragma unroll
      for(int kk=0; kk<NP; kk++){
        short8v kf = *(const short8v*)(Ksh + (h*16+l15)*KP + kk*32 + 8*g);
        s[h] = __builtin_amdgcn_mfma_f32_16x16x32_bf16(qf[kk], kf, s[h], 0,0,0);
      }
    }
    __builtin_amdgcn_s_setprio(0);
    float lmax[4]; bool need = false;
    #pragma unroll
    for(int r=0; r<4; r++){
      float a = fmaxf(s[0][r], s[1][r]);
      lmax[r] = a; need |= (a > m[r] + 8.f);
    }
    if(__any((int)need)){
      #pragma unroll
      for(int r=0; r<4; r++){
        float mx = lmax[r];
        #pragma unroll
        for(int off=1; off<16; off<<=1) mx = fmaxf(mx, __shfl_xor(mx, off));
        float mnew = fmaxf(m[r], mx);
        float scl = exp2f(m[r] - mnew);
        l[r] *= scl; m[r] = mnew;
        #pragma unroll
        for(int ct=0; ct<C/16; ct++) acc[ct][r] *= scl;
      }
    }
    #pragma unroll
    for(int r=0; r<4; r++){
      float e0 = exp2f(s[0][r]-m[r]), e1 = exp2f(s[1][r]-m[r]);
      unsigned pk = pkbf(e0,e1);
      u16* pr = ps[wid] + (4*g+r)*PSP + l15;
      pr[0] = (u16)pk; pr[16] = (u16)(pk>>16);
      l[r] += e0+e1;
    }
    __builtin_amdgcn_s_setprio(1);
    short8v pa = *(const short8v*)(ps[wid] + l15*PSP + 8*g);
    #pragma unroll
    for(int ct=0; ct<C/16; ct++){
      short8v vb;
      if constexpr(VL) vb = *(const short8v*)(Vth + (ct*16+l15)*VP + 8*g);
      else             vb = *(const short8v*)(Vb + (size_t)(ct*16+l15)*N + m0 + 8*g);
      acc[ct] = __builtin_amdgcn_mfma_f32_16x16x32_bf16(pa, vb, acc[ct], 0,0,0);
    }
    __builtin_amdgcn_s_setprio(0);
  }
  #undef APREF
  #pragma unroll
  for(int r=0; r<4; r++){
    float lr = l[r];
    #pragma unroll
    for(int off=1; off<16; off<<=1) lr += __shfl_xor(lr, off);
    l[r] = lr;
  }
  float* accb = (float*)Ks;                // [2][16][CP4]
  float* mlb  = (float*)ps;                // [32][2]
  __syncthreads();
  if(half == 1){
    #pragma unroll
    for(int ct=0; ct<C/16; ct++){
      #pragma unroll
      for(int r=0; r<4; r++)
        accb[(size_t)(qgrp*16 + 4*g + r)*CP4 + ct*16 + l15] = acc[ct][r];
    }
    if(l15 == 0){
      #pragma unroll
      for(int r=0; r<4; r++){
        mlb[(qgrp*16 + 4*g + r)*2]     = m[r];
        mlb[(qgrp*16 + 4*g + r)*2 + 1] = l[r];
      }
    }
  }
  __syncthreads();
  if(half == 0){
    float fa[4], fb[4], inv[4];
    #pragma unroll
    for(int r=0; r<4; r++){
      int row = qgrp*16 + 4*g + r;
      float mb = mlb[row*2], lb = mlb[row*2 + 1];
      float ms = fmaxf(m[r], mb);
      fa[r] = exp2f(m[r] - ms); fb[r] = exp2f(mb - ms);
      inv[r] = 0.5f/(l[r]*fa[r] + lb*fb[r]);
    }
    #pragma unroll
    for(int ct=0; ct<C/16; ct++){
      int c = ct*16 + l15;
      #pragma unroll
      for(int r=0; r<4; r++){
        int row = qgrp*16 + 4*g + r;
        float o = acc[ct][r]*fa[r] + accb[(size_t)row*CP4 + c]*fb[r];
        atomicAdd(&ctxn[((size_t)p*N + q0 + 4*g + r)*C + c], o*inv[r]);
      }
    }
  }
}

// ---------- MFMA flash attn (C=512), exp2 domain ----------
template<int C>
__global__ __launch_bounds__(256) void k_attn_mfma(const u16* __restrict__ Q,
                                                   const u16* __restrict__ K,
                                                   const u16* __restrict__ VT,
                                                   float* __restrict__ ctxn, int N){
  constexpr int KP = C + 8;
  __shared__ u16 Ks[32*KP];
  __shared__ u16 Vt[C*40];
  __shared__ u16 ps[4][16*40];
  int t = threadIdx.x, wid = t>>6, lane = t&63;
  int l15 = lane&15, g = lane>>4;
  int p = blockIdx.y, j = blockIdx.z;
  int q0 = (blockIdx.x*4 + wid)*16;
  const u16* Qb = Q + ((size_t)(p+1)*N + q0)*C;
  const u16* Kb = K  + (size_t)(p + (j?2:0))*N*C;
  const u16* Vb = VT + (size_t)(p + (j?2:0))*C*N;

  short8v qf[C/32];
  #pragma unroll
  for(int kk = 0; kk < C/32; kk++)
    qf[kk] = *(const short8v*)(Qb + (size_t)l15*C + kk*32 + 8*g);

  f32x4 acc[C/16];
  #pragma unroll
  for(int i = 0; i < C/16; i++) acc[i] = f32x4{0.f,0.f,0.f,0.f};
  float mrow[4] = {-1e30f,-1e30f,-1e30f,-1e30f};
  float lrow[4] = {0.f,0.f,0.f,0.f};

  for(int m0 = 0; m0 < N; m0 += 32){
    __syncthreads();
    for(int idx = t*8; idx < 32*C; idx += 2048){
      int m = idx/C, c = idx - m*C;
      *(short8v*)(Ks + m*KP + c) = *(const short8v*)(Kb + (size_t)(m0+m)*C + c);
    }
    for(int idx = t*8; idx < 32*C; idx += 2048){
      int c = idx >> 5, mo = idx & 31;
      *(short8v*)(Vt + c*40 + mo) = *(const short8v*)(Vb + (size_t)c*N + m0 + mo);
    }
    __syncthreads();
    f32x4 s0 = {0.f,0.f,0.f,0.f}, s1 = {0.f,0.f,0.f,0.f};
    #pragma unroll
    for(int kk = 0; kk < C/32; kk++){
      short8v k0 = *(const short8v*)(Ks + l15*KP      + kk*32 + 8*g);
      short8v k1 = *(const short8v*)(Ks + (16+l15)*KP + kk*32 + 8*g);
      s0 = __builtin_amdgcn_mfma_f32_16x16x32_bf16(qf[kk], k0, s0, 0,0,0);
      s1 = __builtin_amdgcn_mfma_f32_16x16x32_bf16(qf[kk], k1, s1, 0,0,0);
    }
    float scl[4];
    #pragma unroll
    for(int r = 0; r < 4; r++){
      float mx = fmaxf(s0[r], s1[r]);
      #pragma unroll
      for(int off = 1; off < 16; off <<= 1) mx = fmaxf(mx, __shfl_xor(mx, off));
      float mnew = fmaxf(mrow[r], mx);
      scl[r] = exp2f(mrow[r] - mnew);
      float e0 = exp2f(s0[r] - mnew), e1 = exp2f(s1[r] - mnew);
      float psum = e0 + e1;
      #pragma unroll
      for(int off = 1; off < 16; off <<= 1) psum += __shfl_xor(psum, off);
      lrow[r] = lrow[r]*scl[r] + psum;
      mrow[r] = mnew;
      unsigned pk = pkbf(e0,e1);
      u16* pr = ps[wid] + (4*g+r)*40 + l15;
      pr[0] = (u16)pk; pr[16] = (u16)(pk>>16);
    }
    #pragma unroll
    for(int ct = 0; ct < C/16; ct++){
      #pragma unroll
      for(int r = 0; r < 4; r++) acc[ct][r] *= scl[r];
    }
    short8v pa = *(const short8v*)(ps[wid] + l15*40 + 8*g);
    #pragma unroll
    for(int ct = 0; ct < C/16; ct++){
      short8v vb = *(const short8v*)(Vt + (ct*16+l15)*40 + 8*g);
      acc[ct] = __builtin_amdgcn_mfma_f32_16x16x32_bf16(pa, vb, acc[ct], 0,0,0);
    }
  }
  #pragma unroll
  for(int ct = 0; ct < C/16; ct++){
    int c = ct*16 + l15;
    #pragma unroll
    for(int r = 0; r < 4; r++){
      int m = 4*g + r;
      atomicAdd(&ctxn[((size_t)p*N + q0 + m)*C + c], 0.5f*acc[ct][r]/lrow[r]);
    }
  }
}

// ---------- fused LayerNorm + p-mean: ctxn[4][N][C] -> cm[N][C] ----------
__global__ __launch_bounds__(256) void k_lncm(const float* __restrict__ ctxn,
                                              fp lng, fp lnb,
                                              float* __restrict__ cm, int C, int N){
  __shared__ float sbuf[4*512];
  int n = blockIdx.x, w = threadIdx.x>>6, lane = threadIdx.x&63;
  const float* row = ctxn + ((size_t)w*N + n)*C;
  float s = 0.f, s2 = 0.f;
  for(int c = lane; c < C; c += 64){ float v = row[c]; s += v; s2 += v*v; }
  #pragma unroll
  for(int off = 32; off > 0; off >>= 1){ s += __shfl_xor(s, off); s2 += __shfl_xor(s2, off); }
  float m = s/(float)C, ri = rsqrtf(s2/(float)C - m*m + 1e-5f);
  for(int c = lane; c < C; c += 64)
    sbuf[w*C + c] = (row[c] - m)*ri*lng[c] + lnb[c];
  __syncthreads();
  for(int c = threadIdx.x; c < C; c += 256)
    cm[(size_t)n*C + c] = 0.25f*(sbuf[c] + sbuf[C+c] + sbuf[2*C+c] + sbuf[3*C+c]);
}

// ---------- h[b][c][n] += cm[n][c], fused per-channel stat accumulation ----------
__global__ __launch_bounds__(256) void k_addstat(float* __restrict__ h, const float* __restrict__ cm,
                                                 float* __restrict__ ss2, int C, int N){
  int bc = blockIdx.x; int c = bc % C;
  float* hp = h + (size_t)bc*N;
  float s = 0.f, s2 = 0.f;
  for(int n = threadIdx.x; n < N; n += blockDim.x){
    float v = hp[n] + cm[(size_t)n*C + c];
    hp[n] = v; s += v; s2 += v*v;
  }
  #pragma unroll
  for(int o = 32; o > 0; o >>= 1){ s += __shfl_down(s, o); s2 += __shfl_down(s2, o); }
  if((threadIdx.x & 63) == 0){
    atomicAdd(&ss2[c], s); atomicAdd(&ss2[C + c], s2);
  }
}
// ---------- finish BN scale/shift from raw sums ----------
__global__ void k_bnfin(const float* __restrict__ ss2, fp bng, fp bnb,
                        float* __restrict__ ss, int C, int N){
  int c = threadIdx.x;
  if(c >= C) return;
  float inv = 1.f/(6.f*(float)N);
  float m = ss2[c]*inv, var = ss2[C+c]*inv - m*m;
  float sc = bng[c]*rsqrtf(var + 1e-5f);
  ss[c] = sc; ss[C + c] = bnb[c] - m*sc;
}

// ---------- BN apply + ReLU, in place; also emit bf16 copy ----------
__global__ __launch_bounds__(256) void k_bnrelu2(float* __restrict__ h, const float* __restrict__ ssin,
                                                 u16* __restrict__ ob, int C, int N){
  int bc = blockIdx.x; int c = bc % C;
  float sc = ssin[c], sh = ssin[C + c];
  float* hp = h + (size_t)bc*N;
  u16* op = ob + (size_t)bc*N;
  for(int n = threadIdx.x; n < N; n += blockDim.x){
    float v = hp[n]*sc + sh; v = v > 0.f ? v : 0.f;
    hp[n] = v; op[n] = f2b(v);
  }
}

// ---------- final up2 + f32 store ----------
__global__ __launch_bounds__(256) void k_up_out(const float* __restrict__ in, float* out,
                                                int H, int W){
  int bc = blockIdx.x;
  const float* ip = in + (size_t)bc*H*W;
  float* op = out + (size_t)bc*4*H*W;
  int W2 = 2*W, N2 = 4*H*W;
  for(int p = threadIdx.x; p < N2; p += blockDim.x){
    int y = p / W2, x = p % W2;
    op[p] = ip[(y>>1)*W + (x>>1)];
  }
}

extern "C" void kernel_launch(void* const* d_in, const int* in_sizes, int n_in,
                              void* d_out, int out_size, void* d_ws, size_t ws_size,
                              hipStream_t stream){
  float* out_f = (float*)d_out;
  static const int EXP[36] = {294912,393216,786432,1572864,3538944,512,
    131072,256,262144,262144,262144,512,512,512,512,1179648,
    32768,128,65536,65536,65536,256,256,256,256,294912,
    8192,64,16384,16384,16384,128,128,128,128,73728};
  bool ok = (n_in == 36) && (out_size == 6291456);
  if(ok) for(int i = 0; i < 36; i++) if(in_sizes[i] != EXP[i]){ ok = false; break; }
  if(!ok){
    k_fill<<<(out_size+255)/256, 256, 0, stream>>>(out_f, out_size, 10.0f);
    return;
  }
  const size_t R = 3145728;
  const size_t NEED = (5*R + 4096)*sizeof(float);
  if(ws_size < NEED){
    k_fill<<<(out_size+255)/256, 256, 0, stream>>>(out_f, out_size, 100.0f);
    return;
  }
  (void)hipGetLastError();
  #define CKERR(code) do{ if(hipGetLastError() != hipSuccess){ \
      k_fill<<<(out_size+255)/256, 256, 0, stream>>>(out_f, out_size, (float)(code)); \
      return; } }while(0)

  fp x = (fp)d_in[0];
  fp skip[3]  = {(fp)d_in[1],(fp)d_in[2],(fp)d_in[3]};
  fp w_sc = (fp)d_in[4], b_sc = (fp)d_in[5];
  fp w_up[3] = {(fp)d_in[6], (fp)d_in[16],(fp)d_in[26]};
  fp b_up[3] = {(fp)d_in[7], (fp)d_in[17],(fp)d_in[27]};
  fp wq[3]   = {(fp)d_in[8], (fp)d_in[18],(fp)d_in[28]};
  fp wk[3]   = {(fp)d_in[9], (fp)d_in[19],(fp)d_in[29]};
  fp wv[3]   = {(fp)d_in[10],(fp)d_in[20],(fp)d_in[30]};
  fp lng[3]  = {(fp)d_in[11],(fp)d_in[21],(fp)d_in[31]};
  fp lnb[3]  = {(fp)d_in[12],(fp)d_in[22],(fp)d_in[32]};
  fp bng[3]  = {(fp)d_in[13],(fp)d_in[23],(fp)d_in[33]};
  fp bnb[3]  = {(fp)d_in[14],(fp)d_in[24],(fp)d_in[34]};
  fp w_cb[3] = {(fp)d_in[15],(fp)d_in[25],(fp)d_in[35]};

  float* Wp = (float*)d_ws;
  float *Cc = Wp, *CT = Wp + R;
  u16 *QB = (u16*)(Wp + 2*R), *KB = (u16*)(Wp + 3*R), *VB = (u16*)(Wp + 4*R);
  float *SS  = Wp + 5*R;
  float *SS2 = Wp + 5*R + 2048;
  float *OB = Wp + R, *Bf = Wp + 2*R, *CM = Wp + 2*R;   // aliases (liveness-verified)
  u16 *XB  = QB + R;
  u16 *WQT = KB + R;
  u16 *WT = KB, *IB = VB;

  // stage 0
  k_in_tr<<<dim3(64,6),256,0,stream>>>(x, Cc);
  k_b16<<<(294912/8+255)/256, 256, 0, stream>>>(Cc, IB, 294912);
  k_wtr<<<(9*512*768+255)/256, 256, 0, stream>>>(w_sc, WT, 512, 768);
  k_fillb<<<(6*512*64+255)/256, 256, 0, stream>>>(OB, b_sc, 512, 64);
  k_conv3_mfma2<<<dim3(1,8,6*8), 256, 0, stream>>>(WT, IB, OB, 768, 512, 8, 8, 8);
  CKERR(20);

  const int Cskip[3] = {256,128,64};
  const int Hs[3]    = {16,32,64};
  const int SPL[3]   = {4,2,1};
  int Cprev = 512;
  for(int i = 0; i < 3; i++){
    int H = Hs[i], N = H*H;
    int N1 = N/4;
    int Cup = Cprev/2;
    int C = Cup + Cskip[i];
    k_conv1_low<<<6*Cup, (N1<256?N1:256), Cprev*4, stream>>>(OB, w_up[i], b_up[i], Bf, Cprev, Cup, N1);
    k_concat_up<<<6*C, 256, 0, stream>>>(Bf, skip[i], Cc, Cup, Cskip[i], N, H);
    k_trb<<<dim3(N/32, C/32, 6), 256, 0, stream>>>(Cc, XB, C, N);
    float rsv = 1.44269504f/sqrtf((float)C);   // fold log2(e) into Q scale (exp2 domain)
    k_wqkvt<<<(3*C*C+255)/256, 256, 0, stream>>>(wq[i], wk[i], wv[i], WQT, C, rsv);
    k_gemm_qkv<<<dim3(6*N/64, 3*C/64), 256, 0, stream>>>(XB, WQT, QB, KB, VB, C, N);
    CKERR(30 + 10*i);
    k_fill<<<(4*N*C+255)/256, 256, 0, stream>>>(CT, 4*N*C, 0.f);
    if(i==0) k_attn_mfma<512><<<dim3(N/64,4,2),256,0,stream>>>(QB,KB,VB,CT,N);
    if(i==1) k_attn_sp<256,false><<<dim3(N/32,4,2),256,0,stream>>>(QB,KB,VB,CT,N);
    if(i==2) k_attn128<<<dim3(N/64,4,2),256,0,stream>>>(QB,KB,VB,CT,N);
    k_lncm<<<N, 256, 0, stream>>>(CT, lng[i], lnb[i], CM, C, N);
    CKERR(32 + 10*i);
    k_fill<<<(2*C+255)/256, 256, 0, stream>>>(SS2, 2*C, 0.f);
    k_addstat<<<6*C, 256, 0, stream>>>(Cc, CM, SS2, C, N);
    k_bnfin<<<1, C, 0, stream>>>(SS2, bng[i], bnb[i], SS, C, N);
    k_bnrelu2<<<6*C, 256, 0, stream>>>(Cc, SS, IB, C, N);
    int Co = C/2, S = SPL[i];
    k_wtr<<<(9*Co*C+255)/256, 256, 0, stream>>>(w_cb[i], WT, Co, C);
    if(S > 1) k_fill<<<(6*Co*N+255)/256, 256, 0, stream>>>(OB, 6*Co*N, 0.f);
    k_conv3_mfma2<<<dim3(N/64, Co/64, 6*S), 256, 0, stream>>>(WT, IB, OB, C, Co, H, H, S);
    CKERR(34 + 10*i);
    Cprev = Co;
  }
  k_up_out<<<6*64, 256, 0, stream>>>(OB, out_f, 64, 64);
  CKERR(90);
  #undef CKERR
}

// Round 15
// 696.462 us; speedup vs baseline: 1.0170x; 1.0170x over previous
//
#include <hip/hip_runtime.h>
#include <hip/hip_bf16.h>

typedef const float* fp;
typedef unsigned short u16;
typedef __attribute__((ext_vector_type(8))) short short8v;   // 8 bf16 (4 VGPR)
typedef __attribute__((ext_vector_type(4))) float f32x4;

__device__ __forceinline__ u16 f2b(float f){       // f32 -> bf16 RNE
  union{float f; unsigned u;} x; x.f = f;
  unsigned r = x.u + 0x7FFFu + ((x.u>>16)&1u);
  return (u16)(r>>16);
}
// fast 2^x: single v_exp_f32 (HW approx, ~1 ulp)
__device__ __forceinline__ float ex2(float x){
  float r;
  asm("v_exp_f32 %0, %1" : "=v"(r) : "v"(x));
  return r;
}

// ---------- sentinel fill ----------
__global__ __launch_bounds__(256) void k_fill(float* out, int n, float v){
  int i = blockIdx.x*256 + threadIdx.x;
  if(i < n) out[i] = v;
}
// ---------- per-channel bias fill ----------
__global__ __launch_bounds__(256) void k_fillb(float* out, fp bias, int Cout, int N){
  int i = blockIdx.x*256 + threadIdx.x;
  if(i < 6*Cout*N) out[i] = bias[(i/N)%Cout];
}
// ---------- f32 -> bf16 elementwise ----------
__global__ __launch_bounds__(256) void k_b16(fp in, u16* o, int n){
  int i = (blockIdx.x*256 + threadIdx.x)*8;
  if(i >= n) return;
  u16 tmp[8];
  #pragma unroll
  for(int e=0;e<8;e++) tmp[e] = f2b(in[i+e]);
  *(short8v*)(o+i) = *(const short8v*)tmp;
}
// ---------- conv weight transform: w[Cout][Cin][9] f32 -> wt[9][Cout][Cin] bf16 ----------
__global__ __launch_bounds__(256) void k_wtr(fp w, u16* wt, int Cout, int Cin){
  int idx = blockIdx.x*256 + threadIdx.x;
  int cc = Cout*Cin;
  if(idx >= 9*cc) return;
  int tap = idx / cc, rem = idx - tap*cc;
  wt[idx] = f2b(w[(size_t)rem*9 + tap]);
}
// ---------- qkv weight transform -> BT[3C][C] bf16 (Q rows scaled by log2e/sqrt(C)) ----------
__global__ __launch_bounds__(256) void k_wqkvt(fp wq, fp wk, fp wv, u16* bt, int C, float rs){
  int idx = blockIdx.x*256 + threadIdx.x;
  if(idx >= 3*C*C) return;
  int r = idx / C, ci = idx - r*C;
  int sel = r / C, co = r - sel*C;
  float v = (sel==0 ? wq : sel==1 ? wk : wv)[(size_t)ci*C + co];
  bt[idx] = f2b(sel==0 ? v*rs : v);
}

// ---------- input transpose: x [6,64,768] f32 -> h0 [6,768,64] f32 ----------
__global__ __launch_bounds__(256) void k_in_tr(fp x, float* h0){
  int n = blockIdx.x, b = blockIdx.y;
  for(int d = threadIdx.x; d < 768; d += blockDim.x)
    h0[((size_t)b*768 + d)*64 + n] = x[((size_t)b*64 + n)*768 + d];
}

// ---------- tap-decomposed implicit-GEMM MFMA 3x3 conv, split-K ----------
__global__ __launch_bounds__(256) void k_conv3_mfma2(const u16* __restrict__ wt,
    const u16* __restrict__ inb16, float* __restrict__ out,
    int Cin, int Cout, int H, int W, int S){
  const int N = H*W;
  __shared__ u16 As[64*40];
  __shared__ u16 Bs[64*40];
  int t = threadIdx.x, wid = t>>6, lane = t&63, l15 = lane&15, g = lane>>4;
  int b = blockIdx.z / S, s = blockIdx.z % S;
  int co0 = blockIdx.y*64, px0 = blockIdx.x*64;
  int ciN = Cin/S, ci0 = s*ciN;
  const u16* inb = inb16 + (size_t)b*Cin*N;
  int arow = t>>2, acol = (t&3)*8;
  int bpx = t&63, boct = t>>6;
  int p = px0 + bpx, py = p/W, px_ = p - py*W;
  int nc = ciN >> 5, nk = 9*nc;
  f32x4 acc[4];
  #pragma unroll
  for(int i=0;i<4;i++) acc[i] = f32x4{0.f,0.f,0.f,0.f};
  short8v av; u16 bt[8];

  #define PREF(ks) { int tap = (ks)/nc; int c0 = ((ks) - tap*nc)<<5;                     \
      int dy = tap/3 - 1, dx = tap - (tap/3)*3 - 1;                                      \
      av = *(const short8v*)(wt + ((size_t)tap*Cout + co0 + arow)*Cin + ci0 + c0 + acol);\
      bool val = ((unsigned)(py+dy) < (unsigned)H) && ((unsigned)(px_+dx) < (unsigned)W);\
      const u16* bp = inb + (size_t)(ci0 + c0 + boct*8)*N + (p + dy*W + dx);             \
      _Pragma("unroll") for(int e=0;e<8;e++) bt[e] = val ? bp[(size_t)e*N] : (u16)0; }

  PREF(0);
  for(int ks = 0; ks < nk; ks++){
    __syncthreads();
    *(short8v*)(As + arow*40 + acol) = av;
    *(short8v*)(Bs + bpx*40 + boct*8) = *(const short8v*)bt;
    __syncthreads();
    if(ks+1 < nk) PREF(ks+1);
    short8v a = *(const short8v*)(As + (wid*16+l15)*40 + 8*g);
    #pragma unroll
    for(int pt=0; pt<4; pt++){
      short8v bf = *(const short8v*)(Bs + (pt*16+l15)*40 + 8*g);
      acc[pt] = __builtin_amdgcn_mfma_f32_16x16x32_bf16(a, bf, acc[pt], 0,0,0);
    }
  }
  #undef PREF
  #pragma unroll
  for(int pt=0; pt<4; pt++){
    #pragma unroll
    for(int r=0; r<4; r++){
      size_t o = ((size_t)b*Cout + co0 + wid*16 + 4*g + r)*N + px0 + pt*16 + l15;
      if(S == 1) out[o] = acc[pt][r];
      else atomicAdd(out + o, acc[pt][r]);
    }
  }
}

// ---------- QKV projection GEMM: XB[6N][C] @ BT[3C][C]^T -> Q,K bf16; V stored TRANSPOSED ----------
__global__ __launch_bounds__(256) void k_gemm_qkv(const u16* __restrict__ XB,
    const u16* __restrict__ BT, u16* __restrict__ Qo, u16* __restrict__ Ko,
    u16* __restrict__ Vo, int C, int Nn){
  __shared__ u16 As[64*40], Bs[64*40];
  int t = threadIdx.x, wid = t>>6, lane = t&63, l15 = lane&15, g = lane>>4;
  int r0 = blockIdx.x*64, c0 = blockIdx.y*64;
  int arow = t>>2, acol = (t&3)*8;
  int nk = C/32;
  f32x4 acc[4];
  #pragma unroll
  for(int i=0;i<4;i++) acc[i] = f32x4{0.f,0.f,0.f,0.f};
  short8v av = *(const short8v*)(XB + (size_t)(r0+arow)*C + acol);
  short8v bv = *(const short8v*)(BT + (size_t)(c0+arow)*C + acol);
  for(int ks = 0; ks < nk; ks++){
    __syncthreads();
    *(short8v*)(As + arow*40 + acol) = av;
    *(short8v*)(Bs + arow*40 + acol) = bv;
    __syncthreads();
    if(ks+1 < nk){
      int k0 = (ks+1)*32;
      av = *(const short8v*)(XB + (size_t)(r0+arow)*C + k0 + acol);
      bv = *(const short8v*)(BT + (size_t)(c0+arow)*C + k0 + acol);
    }
    short8v a = *(const short8v*)(As + (wid*16+l15)*40 + 8*g);
    #pragma unroll
    for(int pt=0; pt<4; pt++){
      short8v bf = *(const short8v*)(Bs + (pt*16+l15)*40 + 8*g);
      acc[pt] = __builtin_amdgcn_mfma_f32_16x16x32_bf16(a, bf, acc[pt], 0,0,0);
    }
  }
  int sel = c0 / C, cb = c0 - sel*C;
  if(sel < 2){
    u16* ob = sel==0 ? Qo : Ko;
    #pragma unroll
    for(int pt=0; pt<4; pt++){
      #pragma unroll
      for(int r=0; r<4; r++)
        ob[(size_t)(r0 + wid*16 + 4*g + r)*C + cb + pt*16 + l15] = f2b(acc[pt][r]);
    }
  }else{
    int b = r0 / Nn, nb = r0 - b*Nn;
    #pragma unroll
    for(int pt=0; pt<4; pt++){
      #pragma unroll
      for(int r=0; r<4; r++)
        Vo[((size_t)b*C + cb + pt*16 + l15)*Nn + nb + wid*16 + 4*g + r] = f2b(acc[pt][r]);
    }
  }
}

// ---------- 1x1 conv at LOW res ----------
__global__ void k_conv1_low(const float* __restrict__ in, fp w, fp bias,
                            float* __restrict__ out, int Cin, int Cout, int N1){
  int bc = blockIdx.x; int b = bc / Cout; int co = bc % Cout;
  extern __shared__ float ws[];
  for(int i = threadIdx.x; i < Cin; i += blockDim.x) ws[i] = w[(size_t)co*Cin + i];
  __syncthreads();
  const float* inb = in + (size_t)b*Cin*N1;
  float bv = bias[co];
  for(int p = threadIdx.x; p < N1; p += blockDim.x){
    float acc = bv;
    for(int ci = 0; ci < Cin; ci++) acc += inb[(size_t)ci*N1 + p] * ws[ci];
    out[((size_t)b*Cout + co)*N1 + p] = acc;
  }
}

// ---------- concat channels with up2 replication of low-res part ----------
__global__ __launch_bounds__(256) void k_concat_up(const float* __restrict__ a, fp skip,
                                                   float* __restrict__ cat,
                                                   int Ca, int Cs, int N2, int W2){
  int bc = blockIdx.x; int C = Ca + Cs; int b = bc / C; int c = bc % C;
  float* o = cat + (size_t)bc*N2;
  if(c < Ca){
    const float* s = a + ((size_t)b*Ca + c)*(N2/4);
    int W1 = W2/2;
    for(int n = threadIdx.x; n < N2; n += blockDim.x){
      int y = n / W2, x = n % W2;
      o[n] = s[(y>>1)*W1 + (x>>1)];
    }
  }else{
    fp s = skip + ((size_t)b*Cs + (c-Ca))*N2;
    for(int n = threadIdx.x; n < N2; n += blockDim.x) o[n] = s[n];
  }
}

// ---------- tiled transpose+bf16: [6][C][N] f32 -> [6][N][C] bf16 ----------
__global__ __launch_bounds__(256) void k_trb(const float* __restrict__ src, u16* __restrict__ dst,
                                             int C, int N){
  __shared__ float tb[32][33];
  int b = blockIdx.z;
  int c0 = blockIdx.y*32, n0 = blockIdx.x*32;
  int tx = threadIdx.x & 31, ty = threadIdx.x >> 5;
  for(int i = ty; i < 32; i += 8) tb[i][tx] = src[((size_t)b*C + c0+i)*N + n0+tx];
  __syncthreads();
  for(int i = ty; i < 32; i += 8) dst[((size_t)b*N + n0+i)*C + c0+tx] = f2b(tb[tx][i]);
}

// ---------- MFMA flash attn C=128: exp2 domain via raw v_exp, f2b ps stores ----------
__global__ __launch_bounds__(256) void k_attn128(const u16* __restrict__ Q,
                                                 const u16* __restrict__ K,
                                                 const u16* __restrict__ VT,
                                                 float* __restrict__ ctxn, int N){
  constexpr int C = 128, KVB = 64, KP = C+8, VP = KVB+8, PSP = 68;
  __shared__ u16 Ks[KVB*KP];      // [m][c]
  __shared__ u16 Vt[C*VP];        // [c][m]
  __shared__ u16 ps[4][16*PSP];
  int t = threadIdx.x, wid = t>>6, lane = t&63, l15 = lane&15, g = lane>>4;
  int p = blockIdx.y, q0 = (blockIdx.x*4 + wid)*16, j = blockIdx.z;
  const u16* Qb = Q + ((size_t)(p+1)*N + q0)*C;
  const u16* Kb = K  + (size_t)(p + (j?2:0))*N*C;   // [N][C]
  const u16* Vb = VT + (size_t)(p + (j?2:0))*C*N;   // [C][N]
  short8v qf[4];
  #pragma unroll
  for(int kk = 0; kk < 4; kk++)
    qf[kk] = *(const short8v*)(Qb + (size_t)l15*C + kk*32 + 8*g);
  f32x4 acc[8];
  #pragma unroll
  for(int i=0;i<8;i++) acc[i] = f32x4{0.f,0.f,0.f,0.f};
  float m[4] = {-1e30f,-1e30f,-1e30f,-1e30f};
  float l[4] = {0.f,0.f,0.f,0.f};         // lane-local partial sums
  short8v kpre[4], vpre[4];

  #define APREF(M0) { _Pragma("unroll") for(int i=0;i<4;i++){                  \
        int idx = t*8 + i*2048; int mm = idx>>7, cc = idx&127;                 \
        kpre[i] = *(const short8v*)(Kb + (size_t)((M0)+mm)*C + cc); }          \
      _Pragma("unroll") for(int i=0;i<4;i++){                                  \
        int idx = t*8 + i*2048; int c = idx>>6, mo = idx&63;                   \
        vpre[i] = *(const short8v*)(Vb + (size_t)c*N + (M0) + mo); } }

  APREF(0);
  for(int m0 = 0; m0 < N; m0 += KVB){
    __syncthreads();
    #pragma unroll
    for(int i=0;i<4;i++){ int idx = t*8 + i*2048; int mm = idx>>7, cc = idx&127;
      *(short8v*)(Ks + mm*KP + cc) = kpre[i]; }
    #pragma unroll
    for(int i=0;i<4;i++){ int idx = t*8 + i*2048; int c = idx>>6, mo = idx&63;
      *(short8v*)(Vt + c*VP + mo) = vpre[i]; }
    __syncthreads();
    if(m0 + KVB < N) APREF(m0 + KVB);
    f32x4 s[4];
    __builtin_amdgcn_s_setprio(1);
    #pragma unroll
    for(int h=0; h<4; h++){
      s[h] = f32x4{0.f,0.f,0.f,0.f};
      #pragma unroll
      for(int kk=0; kk<4; kk++){
        short8v kf = *(const short8v*)(Ks + (h*16+l15)*KP + kk*32 + 8*g);
        s[h] = __builtin_amdgcn_mfma_f32_16x16x32_bf16(qf[kk], kf, s[h], 0,0,0);
      }
    }
    __builtin_amdgcn_s_setprio(0);
    float lmax[4]; bool need = false;
    #pragma unroll
    for(int r=0; r<4; r++){
      float a = fmaxf(fmaxf(s[0][r],s[1][r]), fmaxf(s[2][r],s[3][r]));
      lmax[r] = a; need |= (a > m[r] + 8.f);
    }
    if(__any((int)need)){
      #pragma unroll
      for(int r=0; r<4; r++){
        float mx = lmax[r];
        #pragma unroll
        for(int off=1; off<16; off<<=1) mx = fmaxf(mx, __shfl_xor(mx, off));
        float mnew = fmaxf(m[r], mx);
        float scl = ex2(m[r] - mnew);
        l[r] *= scl; m[r] = mnew;
        #pragma unroll
        for(int ct=0; ct<8; ct++) acc[ct][r] *= scl;
      }
    }
    #pragma unroll
    for(int r=0; r<4; r++){
      float ls = 0.f;
      #pragma unroll
      for(int h=0; h<4; h++){
        float e = ex2(s[h][r] - m[r]); ls += e;
        ps[wid][(4*g+r)*PSP + h*16 + l15] = f2b(e);
      }
      l[r] += ls;
    }
    __builtin_amdgcn_s_setprio(1);
    #pragma unroll
    for(int ks=0; ks<2; ks++){
      short8v pa = *(const short8v*)(ps[wid] + l15*PSP + ks*32 + 8*g);
      #pragma unroll
      for(int ct=0; ct<8; ct++){
        short8v vb = *(const short8v*)(Vt + (ct*16+l15)*VP + ks*32 + 8*g);
        acc[ct] = __builtin_amdgcn_mfma_f32_16x16x32_bf16(pa, vb, acc[ct], 0,0,0);
      }
    }
    __builtin_amdgcn_s_setprio(0);
  }
  #undef APREF
  float inv[4];
  #pragma unroll
  for(int r=0; r<4; r++){
    float lr = l[r];
    #pragma unroll
    for(int off=1; off<16; off<<=1) lr += __shfl_xor(lr, off);
    inv[r] = 0.5f/lr;
  }
  #pragma unroll
  for(int ct=0; ct<8; ct++){
    int c = ct*16 + l15;
    #pragma unroll
    for(int r=0; r<4; r++)
      atomicAdd(&ctxn[((size_t)p*N + q0 + 4*g + r)*C + c], acc[ct][r]*inv[r]);
  }
}

// ---------- MFMA flash attn, in-block KV-split-2 (C=256), exp2 domain via v_exp ----------
template<int C, bool VL>
__global__ __launch_bounds__(256) void k_attn_sp(const u16* __restrict__ Q,
    const u16* __restrict__ K, const u16* __restrict__ VT,
    float* __restrict__ ctxn, int N){
  constexpr int KVB = 32, KP = C+8, VP = 40, PSP = 40, NP = C/32, CP4 = C+4;
  __shared__ u16 Ks[2*KVB*KP];
  __shared__ u16 Vt[VL ? 2*C*VP : 8];
  __shared__ u16 ps[4][16*PSP];
  int t = threadIdx.x, wid = t>>6, lane = t&63, l15 = lane&15, g = lane>>4;
  int half = wid & 1, qgrp = wid >> 1;
  int lt = ((t>>7)<<6) | (t&63);
  int p = blockIdx.y, j = blockIdx.z;
  int q0 = (blockIdx.x*2 + qgrp)*16;
  const u16* Qb = Q + ((size_t)(p+1)*N + q0)*C;
  const u16* Kb = K  + (size_t)(p + (j?2:0))*N*C;
  const u16* Vb = VT + (size_t)(p + (j?2:0))*C*N;
  u16* Ksh = Ks + half*(KVB*KP);
  u16* Vth = Vt + (VL ? half*(C*VP) : 0);
  int kbase = half*(N>>1);

  short8v qf[NP];
  #pragma unroll
  for(int kk=0;kk<NP;kk++)
    qf[kk] = *(const short8v*)(Qb + (size_t)l15*C + kk*32 + 8*g);
  f32x4 acc[C/16];
  #pragma unroll
  for(int i=0;i<C/16;i++) acc[i] = f32x4{0.f,0.f,0.f,0.f};
  float m[4] = {-1e30f,-1e30f,-1e30f,-1e30f};
  float l[4] = {0.f,0.f,0.f,0.f};
  short8v kpre[NP], vpre[NP];

  #define APREF(M0) { _Pragma("unroll") for(int i_=0;i_<NP;i_++){                 \
        int idx = lt*8 + i_*1024; int mm = idx/C, cc = idx - mm*C;                \
        kpre[i_] = *(const short8v*)(Kb + (size_t)((M0)+mm)*C + cc); }            \
      if constexpr(VL){ _Pragma("unroll") for(int i_=0;i_<NP;i_++){               \
        int idx = lt*8 + i_*1024; int c = idx>>5, mo = idx&31;                    \
        vpre[i_] = *(const short8v*)(Vb + (size_t)c*N + (M0) + mo); } } }

  const int nit = N>>6;
  APREF(kbase);
  for(int it = 0; it < nit; ++it){
    int m0 = kbase + it*KVB;
    __syncthreads();
    #pragma unroll
    for(int i_=0;i_<NP;i_++){ int idx = lt*8 + i_*1024; int mm = idx/C, cc = idx - mm*C;
      *(short8v*)(Ksh + mm*KP + cc) = kpre[i_]; }
    if constexpr(VL){
      #pragma unroll
      for(int i_=0;i_<NP;i_++){ int idx = lt*8 + i_*1024; int c = idx>>5, mo = idx&31;
        *(short8v*)(Vth + c*VP + mo) = vpre[i_]; }
    }
    __syncthreads();
    if(it+1 < nit) APREF(kbase + (it+1)*KVB);
    f32x4 s[2];
    __builtin_amdgcn_s_setprio(1);
    #pragma unroll
    for(int h=0; h<2; h++){
      s[h] = f32x4{0.f,0.f,0.f,0.f};
      #pragma unroll
      for(int kk=0; kk<NP; kk++){
        short8v kf = *(const short8v*)(Ksh + (h*16+l15)*KP + kk*32 + 8*g);
        s[h] = __builtin_amdgcn_mfma_f32_16x16x32_bf16(qf[kk], kf, s[h], 0,0,0);
      }
    }
    __builtin_amdgcn_s_setprio(0);
    float lmax[4]; bool need = false;
    #pragma unroll
    for(int r=0; r<4; r++){
      float a = fmaxf(s[0][r], s[1][r]);
      lmax[r] = a; need |= (a > m[r] + 8.f);
    }
    if(__any((int)need)){
      #pragma unroll
      for(int r=0; r<4; r++){
        float mx = lmax[r];
        #pragma unroll
        for(int off=1; off<16; off<<=1) mx = fmaxf(mx, __shfl_xor(mx, off));
        float mnew = fmaxf(m[r], mx);
        float scl = ex2(m[r] - mnew);
        l[r] *= scl; m[r] = mnew;
        #pragma unroll
        for(int ct=0; ct<C/16; ct++) acc[ct][r] *= scl;
      }
    }
    #pragma unroll
    for(int r=0; r<4; r++){
      float e0 = ex2(s[0][r]-m[r]), e1 = ex2(s[1][r]-m[r]);
      ps[wid][(4*g+r)*PSP + l15]      = f2b(e0);
      ps[wid][(4*g+r)*PSP + 16 + l15] = f2b(e1);
      l[r] += e0+e1;
    }
    __builtin_amdgcn_s_setprio(1);
    short8v pa = *(const short8v*)(ps[wid] + l15*PSP + 8*g);
    #pragma unroll
    for(int ct=0; ct<C/16; ct++){
      short8v vb;
      if constexpr(VL) vb = *(const short8v*)(Vth + (ct*16+l15)*VP + 8*g);
      else             vb = *(const short8v*)(Vb + (size_t)(ct*16+l15)*N + m0 + 8*g);
      acc[ct] = __builtin_amdgcn_mfma_f32_16x16x32_bf16(pa, vb, acc[ct], 0,0,0);
    }
    __builtin_amdgcn_s_setprio(0);
  }
  #undef APREF
  #pragma unroll
  for(int r=0; r<4; r++){
    float lr = l[r];
    #pragma unroll
    for(int off=1; off<16; off<<=1) lr += __shfl_xor(lr, off);
    l[r] = lr;
  }
  float* accb = (float*)Ks;                // [2][16][CP4]
  float* mlb  = (float*)ps;                // [32][2]
  __syncthreads();
  if(half == 1){
    #pragma unroll
    for(int ct=0; ct<C/16; ct++){
      #pragma unroll
      for(int r=0; r<4; r++)
        accb[(size_t)(qgrp*16 + 4*g + r)*CP4 + ct*16 + l15] = acc[ct][r];
    }
    if(l15 == 0){
      #pragma unroll
      for(int r=0; r<4; r++){
        mlb[(qgrp*16 + 4*g + r)*2]     = m[r];
        mlb[(qgrp*16 + 4*g + r)*2 + 1] = l[r];
      }
    }
  }
  __syncthreads();
  if(half == 0){
    float fa[4], fb[4], inv[4];
    #pragma unroll
    for(int r=0; r<4; r++){
      int row = qgrp*16 + 4*g + r;
      float mb = mlb[row*2], lb = mlb[row*2 + 1];
      float ms = fmaxf(m[r], mb);
      fa[r] = ex2(m[r] - ms); fb[r] = ex2(mb - ms);
      inv[r] = 0.5f/(l[r]*fa[r] + lb*fb[r]);
    }
    #pragma unroll
    for(int ct=0; ct<C/16; ct++){
      int c = ct*16 + l15;
      #pragma unroll
      for(int r=0; r<4; r++){
        int row = qgrp*16 + 4*g + r;
        float o = acc[ct][r]*fa[r] + accb[(size_t)row*CP4 + c]*fb[r];
        atomicAdd(&ctxn[((size_t)p*N + q0 + 4*g + r)*C + c], o*inv[r]);
      }
    }
  }
}

// ---------- MFMA flash attn (C=512), exp2 domain via v_exp ----------
template<int C>
__global__ __launch_bounds__(256) void k_attn_mfma(const u16* __restrict__ Q,
                                                   const u16* __restrict__ K,
                                                   const u16* __restrict__ VT,
                                                   float* __restrict__ ctxn, int N){
  constexpr int KP = C + 8;
  __shared__ u16 Ks[32*KP];
  __shared__ u16 Vt[C*40];
  __shared__ u16 ps[4][16*40];
  int t = threadIdx.x, wid = t>>6, lane = t&63;
  int l15 = lane&15, g = lane>>4;
  int p = blockIdx.y, j = blockIdx.z;
  int q0 = (blockIdx.x*4 + wid)*16;
  const u16* Qb = Q + ((size_t)(p+1)*N + q0)*C;
  const u16* Kb = K  + (size_t)(p + (j?2:0))*N*C;
  const u16* Vb = VT + (size_t)(p + (j?2:0))*C*N;

  short8v qf[C/32];
  #pragma unroll
  for(int kk = 0; kk < C/32; kk++)
    qf[kk] = *(const short8v*)(Qb + (size_t)l15*C + kk*32 + 8*g);

  f32x4 acc[C/16];
  #pragma unroll
  for(int i = 0; i < C/16; i++) acc[i] = f32x4{0.f,0.f,0.f,0.f};
  float mrow[4] = {-1e30f,-1e30f,-1e30f,-1e30f};
  float lrow[4] = {0.f,0.f,0.f,0.f};

  for(int m0 = 0; m0 < N; m0 += 32){
    __syncthreads();
    for(int idx = t*8; idx < 32*C; idx += 2048){
      int m = idx/C, c = idx - m*C;
      *(short8v*)(Ks + m*KP + c) = *(const short8v*)(Kb + (size_t)(m0+m)*C + c);
    }
    for(int idx = t*8; idx < 32*C; idx += 2048){
      int c = idx >> 5, mo = idx & 31;
      *(short8v*)(Vt + c*40 + mo) = *(const short8v*)(Vb + (size_t)c*N + m0 + mo);
    }
    __syncthreads();
    f32x4 s0 = {0.f,0.f,0.f,0.f}, s1 = {0.f,0.f,0.f,0.f};
    #pragma unroll
    for(int kk = 0; kk < C/32; kk++){
      short8v k0 = *(const short8v*)(Ks + l15*KP      + kk*32 + 8*g);
      short8v k1 = *(const short8v*)(Ks + (16+l15)*KP + kk*32 + 8*g);
      s0 = __builtin_amdgcn_mfma_f32_16x16x32_bf16(qf[kk], k0, s0, 0,0,0);
      s1 = __builtin_amdgcn_mfma_f32_16x16x32_bf16(qf[kk], k1, s1, 0,0,0);
    }
    float scl[4];
    #pragma unroll
    for(int r = 0; r < 4; r++){
      float mx = fmaxf(s0[r], s1[r]);
      #pragma unroll
      for(int off = 1; off < 16; off <<= 1) mx = fmaxf(mx, __shfl_xor(mx, off));
      float mnew = fmaxf(mrow[r], mx);
      scl[r] = ex2(mrow[r] - mnew);
      float e0 = ex2(s0[r] - mnew), e1 = ex2(s1[r] - mnew);
      float psum = e0 + e1;
      #pragma unroll
      for(int off = 1; off < 16; off <<= 1) psum += __shfl_xor(psum, off);
      lrow[r] = lrow[r]*scl[r] + psum;
      mrow[r] = mnew;
      int m = 4*g + r;
      ps[wid][m*40 + l15]      = f2b(e0);
      ps[wid][m*40 + 16 + l15] = f2b(e1);
    }
    #pragma unroll
    for(int ct = 0; ct < C/16; ct++){
      #pragma unroll
      for(int r = 0; r < 4; r++) acc[ct][r] *= scl[r];
    }
    short8v pa = *(const short8v*)(ps[wid] + l15*40 + 8*g);
    #pragma unroll
    for(int ct = 0; ct < C/16; ct++){
      short8v vb = *(const short8v*)(Vt + (ct*16+l15)*40 + 8*g);
      acc[ct] = __builtin_amdgcn_mfma_f32_16x16x32_bf16(pa, vb, acc[ct], 0,0,0);
    }
  }
  #pragma unroll
  for(int ct = 0; ct < C/16; ct++){
    int c = ct*16 + l15;
    #pragma unroll
    for(int r = 0; r < 4; r++){
      int m = 4*g + r;
      atomicAdd(&ctxn[((size_t)p*N + q0 + m)*C + c], 0.5f*acc[ct][r]/lrow[r]);
    }
  }
}

// ---------- fused LayerNorm + p-mean: ctxn[4][N][C] -> cm[N][C] ----------
__global__ __launch_bounds__(256) void k_lncm(const float* __restrict__ ctxn,
                                              fp lng, fp lnb,
                                              float* __restrict__ cm, int C, int N){
  __shared__ float sbuf[4*512];
  int n = blockIdx.x, w = threadIdx.x>>6, lane = threadIdx.x&63;
  const float* row = ctxn + ((size_t)w*N + n)*C;
  float s = 0.f, s2 = 0.f;
  for(int c = lane; c < C; c += 64){ float v = row[c]; s += v; s2 += v*v; }
  #pragma unroll
  for(int off = 32; off > 0; off >>= 1){ s += __shfl_xor(s, off); s2 += __shfl_xor(s2, off); }
  float m = s/(float)C, ri = rsqrtf(s2/(float)C - m*m + 1e-5f);
  for(int c = lane; c < C; c += 64)
    sbuf[w*C + c] = (row[c] - m)*ri*lng[c] + lnb[c];
  __syncthreads();
  for(int c = threadIdx.x; c < C; c += 256)
    cm[(size_t)n*C + c] = 0.25f*(sbuf[c] + sbuf[C+c] + sbuf[2*C+c] + sbuf[3*C+c]);
}

// ---------- h[b][c][n] += cm[n][c], fused per-channel stat accumulation ----------
__global__ __launch_bounds__(256) void k_addstat(float* __restrict__ h, const float* __restrict__ cm,
                                                 float* __restrict__ ss2, int C, int N){
  int bc = blockIdx.x; int c = bc % C;
  float* hp = h + (size_t)bc*N;
  float s = 0.f, s2 = 0.f;
  for(int n = threadIdx.x; n < N; n += blockDim.x){
    float v = hp[n] + cm[(size_t)n*C + c];
    hp[n] = v; s += v; s2 += v*v;
  }
  #pragma unroll
  for(int o = 32; o > 0; o >>= 1){ s += __shfl_down(s, o); s2 += __shfl_down(s2, o); }
  if((threadIdx.x & 63) == 0){
    atomicAdd(&ss2[c], s); atomicAdd(&ss2[C + c], s2);
  }
}
// ---------- finish BN scale/shift from raw sums ----------
__global__ void k_bnfin(const float* __restrict__ ss2, fp bng, fp bnb,
                        float* __restrict__ ss, int C, int N){
  int c = threadIdx.x;
  if(c >= C) return;
  float inv = 1.f/(6.f*(float)N);
  float m = ss2[c]*inv, var = ss2[C+c]*inv - m*m;
  float sc = bng[c]*rsqrtf(var + 1e-5f);
  ss[c] = sc; ss[C + c] = bnb[c] - m*sc;
}

// ---------- BN apply + ReLU, in place; also emit bf16 copy ----------
__global__ __launch_bounds__(256) void k_bnrelu2(float* __restrict__ h, const float* __restrict__ ssin,
                                                 u16* __restrict__ ob, int C, int N){
  int bc = blockIdx.x; int c = bc % C;
  float sc = ssin[c], sh = ssin[C + c];
  float* hp = h + (size_t)bc*N;
  u16* op = ob + (size_t)bc*N;
  for(int n = threadIdx.x; n < N; n += blockDim.x){
    float v = hp[n]*sc + sh; v = v > 0.f ? v : 0.f;
    hp[n] = v; op[n] = f2b(v);
  }
}

// ---------- final up2 + f32 store ----------
__global__ __launch_bounds__(256) void k_up_out(const float* __restrict__ in, float* out,
                                                int H, int W){
  int bc = blockIdx.x;
  const float* ip = in + (size_t)bc*H*W;
  float* op = out + (size_t)bc*4*H*W;
  int W2 = 2*W, N2 = 4*H*W;
  for(int p = threadIdx.x; p < N2; p += blockDim.x){
    int y = p / W2, x = p % W2;
    op[p] = ip[(y>>1)*W + (x>>1)];
  }
}

extern "C" void kernel_launch(void* const* d_in, const int* in_sizes, int n_in,
                              void* d_out, int out_size, void* d_ws, size_t ws_size,
                              hipStream_t stream){
  float* out_f = (float*)d_out;
  static const int EXP[36] = {294912,393216,786432,1572864,3538944,512,
    131072,256,262144,262144,262144,512,512,512,512,1179648,
    32768,128,65536,65536,65536,256,256,256,256,294912,
    8192,64,16384,16384,16384,128,128,128,128,73728};
  bool ok = (n_in == 36) && (out_size == 6291456);
  if(ok) for(int i = 0; i < 36; i++) if(in_sizes[i] != EXP[i]){ ok = false; break; }
  if(!ok){
    k_fill<<<(out_size+255)/256, 256, 0, stream>>>(out_f, out_size, 10.0f);
    return;
  }
  const size_t R = 3145728;
  const size_t NEED = (5*R + 4096)*sizeof(float);
  if(ws_size < NEED){
    k_fill<<<(out_size+255)/256, 256, 0, stream>>>(out_f, out_size, 100.0f);
    return;
  }
  (void)hipGetLastError();
  #define CKERR(code) do{ if(hipGetLastError() != hipSuccess){ \
      k_fill<<<(out_size+255)/256, 256, 0, stream>>>(out_f, out_size, (float)(code)); \
      return; } }while(0)

  fp x = (fp)d_in[0];
  fp skip[3]  = {(fp)d_in[1],(fp)d_in[2],(fp)d_in[3]};
  fp w_sc = (fp)d_in[4], b_sc = (fp)d_in[5];
  fp w_up[3] = {(fp)d_in[6], (fp)d_in[16],(fp)d_in[26]};
  fp b_up[3] = {(fp)d_in[7], (fp)d_in[17],(fp)d_in[27]};
  fp wq[3]   = {(fp)d_in[8], (fp)d_in[18],(fp)d_in[28]};
  fp wk[3]   = {(fp)d_in[9], (fp)d_in[19],(fp)d_in[29]};
  fp wv[3]   = {(fp)d_in[10],(fp)d_in[20],(fp)d_in[30]};
  fp lng[3]  = {(fp)d_in[11],(fp)d_in[21],(fp)d_in[31]};
  fp lnb[3]  = {(fp)d_in[12],(fp)d_in[22],(fp)d_in[32]};
  fp bng[3]  = {(fp)d_in[13],(fp)d_in[23],(fp)d_in[33]};
  fp bnb[3]  = {(fp)d_in[14],(fp)d_in[24],(fp)d_in[34]};
  fp w_cb[3] = {(fp)d_in[15],(fp)d_in[25],(fp)d_in[35]};

  float* Wp = (float*)d_ws;
  float *Cc = Wp, *CT = Wp + R;
  u16 *QB = (u16*)(Wp + 2*R), *KB = (u16*)(Wp + 3*R), *VB = (u16*)(Wp + 4*R);
  float *SS  = Wp + 5*R;
  float *SS2 = Wp + 5*R + 2048;
  float *OB = Wp + R, *Bf = Wp + 2*R, *CM = Wp + 2*R;   // aliases (liveness-verified)
  u16 *XB  = QB + R;
  u16 *WQT = KB + R;
  u16 *WT = KB, *IB = VB;

  // stage 0
  k_in_tr<<<dim3(64,6),256,0,stream>>>(x, Cc);
  k_b16<<<(294912/8+255)/256, 256, 0, stream>>>(Cc, IB, 294912);
  k_wtr<<<(9*512*768+255)/256, 256, 0, stream>>>(w_sc, WT, 512, 768);
  k_fillb<<<(6*512*64+255)/256, 256, 0, stream>>>(OB, b_sc, 512, 64);
  k_conv3_mfma2<<<dim3(1,8,6*8), 256, 0, stream>>>(WT, IB, OB, 768, 512, 8, 8, 8);
  CKERR(20);

  const int Cskip[3] = {256,128,64};
  const int Hs[3]    = {16,32,64};
  const int SPL[3]   = {4,2,1};
  int Cprev = 512;
  for(int i = 0; i < 3; i++){
    int H = Hs[i], N = H*H;
    int N1 = N/4;
    int Cup = Cprev/2;
    int C = Cup + Cskip[i];
    k_conv1_low<<<6*Cup, (N1<256?N1:256), Cprev*4, stream>>>(OB, w_up[i], b_up[i], Bf, Cprev, Cup, N1);
    k_concat_up<<<6*C, 256, 0, stream>>>(Bf, skip[i], Cc, Cup, Cskip[i], N, H);
    k_trb<<<dim3(N/32, C/32, 6), 256, 0, stream>>>(Cc, XB, C, N);
    float rsv = 1.44269504f/sqrtf((float)C);   // fold log2(e) into Q scale (exp2 domain)
    k_wqkvt<<<(3*C*C+255)/256, 256, 0, stream>>>(wq[i], wk[i], wv[i], WQT, C, rsv);
    k_gemm_qkv<<<dim3(6*N/64, 3*C/64), 256, 0, stream>>>(XB, WQT, QB, KB, VB, C, N);
    CKERR(30 + 10*i);
    k_fill<<<(4*N*C+255)/256, 256, 0, stream>>>(CT, 4*N*C, 0.f);
    if(i==0) k_attn_mfma<512><<<dim3(N/64,4,2),256,0,stream>>>(QB,KB,VB,CT,N);
    if(i==1) k_attn_sp<256,false><<<dim3(N/32,4,2),256,0,stream>>>(QB,KB,VB,CT,N);
    if(i==2) k_attn128<<<dim3(N/64,4,2),256,0,stream>>>(QB,KB,VB,CT,N);
    k_lncm<<<N, 256, 0, stream>>>(CT, lng[i], lnb[i], CM, C, N);
    CKERR(32 + 10*i);
    k_fill<<<(2*C+255)/256, 256, 0, stream>>>(SS2, 2*C, 0.f);
    k_addstat<<<6*C, 256, 0, stream>>>(Cc, CM, SS2, C, N);
    k_bnfin<<<1, C, 0, stream>>>(SS2, bng[i], bnb[i], SS, C, N);
    k_bnrelu2<<<6*C, 256, 0, stream>>>(Cc, SS, IB, C, N);
    int Co = C/2, S = SPL[i];
    k_wtr<<<(9*Co*C+255)/256, 256, 0, stream>>>(w_cb[i], WT, Co, C);
    if(S > 1) k_fill<<<(6*Co*N+255)/256, 256, 0, stream>>>(OB, 6*Co*N, 0.f);
    k_conv3_mfma2<<<dim3(N/64, Co/64, 6*S), 256, 0, stream>>>(WT, IB, OB, C, Co, H, H, S);
    CKERR(34 + 10*i);
    Cprev = Co;
  }
  k_up_out<<<6*64, 256, 0, stream>>>(OB, out_f, 64, 64);
  CKERR(90);
  #undef CKERR
}